// Round 6
// baseline (334.229 us; speedup 1.0000x reference)
//
#include <hip/hip_runtime.h>

typedef unsigned short u16;
typedef unsigned int   u32;
typedef __attribute__((ext_vector_type(8))) short short8;
typedef __attribute__((ext_vector_type(4))) float f32x4;
typedef __attribute__((ext_vector_type(4))) u16   u16x4;

#define NB 4
#define SL 4096
#define DM 1024
#define NH 16
#define DK 64

__device__ __forceinline__ u16 f2bf(float f) {
  u32 u = __builtin_bit_cast(u32, f);
  u = (u + 0x7fffu + ((u >> 16) & 1u)) >> 16;
  return (u16)u;
}
__device__ __forceinline__ float bf2f(u16 v) {
  u32 u = ((u32)v) << 16;
  return __builtin_bit_cast(float, u);
}
__device__ __forceinline__ float eluP1(float x) {
  return x > 0.f ? x + 1.f : __expf(x);
}
// NOTE: the imm offset of global_load_lds applies to BOTH global and LDS
// addresses (LLVM intrinsic semantics) — always pass 0 and do pointer math.
#define GLL(gp, lp) __builtin_amdgcn_global_load_lds(     \
    (const __attribute__((address_space(1))) void*)(gp),  \
    (__attribute__((address_space(3))) void*)(lp), 16, 0, 0)

// ---------------- merged conversions ----------------
__global__ void cvt_all(const float* __restrict__ Qf,
                        const float* __restrict__ WQ, const float* __restrict__ WK,
                        const float* __restrict__ WV, const float* __restrict__ WO,
                        const float* __restrict__ bQ, const float* __restrict__ bK,
                        const float* __restrict__ bV,
                        u16* __restrict__ Qbf, u16* __restrict__ Wqkv,
                        u16* __restrict__ Wobf, float* __restrict__ biasQKV) {
  int b = blockIdx.x, tid = threadIdx.x;
  if (b < 16384) {
    int i = b * 256 + tid;
    f32x4 f = *(const f32x4*)(Qf + (size_t)i * 4);
    u16x4 o = { f2bf(f[0]), f2bf(f[1]), f2bf(f[2]), f2bf(f[3]) };
    *(u16x4*)(Qbf + (size_t)i * 4) = o;
  } else if (b < 20480) {
    int r = (b - 16384) >> 10;
    int i = ((b - 16384) & 1023) * 256 + tid;
    const float* src = r == 0 ? WQ : r == 1 ? WK : r == 2 ? WV : WO;
    u16* dst = (r == 3) ? Wobf : Wqkv + (size_t)r * 1048576;
    f32x4 f = *(const f32x4*)(src + (size_t)i * 4);
    u16x4 o = { f2bf(f[0]), f2bf(f[1]), f2bf(f[2]), f2bf(f[3]) };
    *(u16x4*)(dst + (size_t)i * 4) = o;
  } else {
    int i = (b - 20480) * 256 + tid;
    if (i < 3072) {
      float v = (i < 1024) ? bQ[i] : (i < 2048) ? bK[i - 1024] : bV[i - 2048];
      biasQKV[i] = v;
    }
  }
}

// ======== 256x256 reg-dbuf single-barrier 8-phase GEMM template ========
// LDS map (u16 elems): As[buf][ks] @ buf*32768 + ks*8192  ([256 rows][32 k])
//                      Bs[buf][ks] @ 16384 + buf*32768 + ks*8192
// 8 units of 16KB (buf x ks x A/B); 2 GLL/wave per unit stage.
// Phase p = { RD(p+1) ds_reads -> alternate reg set; lgkmcnt(N=|RD(p+1)|)
//             (=> RD(p) complete); sched_barrier; MFMA(p) on current set;
//             stage 1 unit; vmcnt(8); s_barrier }.
// MFMA(p) runs UNDER the in-flight RD(p+1) reads -> DS pipe and MFMA pipe
// overlap (the R5 structure waited lgkm0 on same-phase reads: serial).
// Hazards (derived, unit = stage #):
//  RAW: read at phase q (issued q-1, after barrier(q-2)) needs its unit
//    landed by vmcnt(8)@q-2. Landed units at phase j = 3+j (prologue 7 units
//    =14 GLL, +2 GLL/phase). All read/stage distances satisfy s <= q-6
//    (tightest: A11 s=P1 q=P7; A00' s=P3 q=next-P1; checked per unit).
//  WAR: restage at s issued after barrier(s-1); last read of that unit was
//    ISSUED at s-2 and WAITED at lgkm in s-1 before barrier(s-1). All units
//    restage exactly at last-read-issue+2. (bf reads once per 2 phases.)
// Stage rotation (iter i, kt=2i): P1:A(1,1,2i+1) P2:B(0,0,2i+2) P3:A(0,0,2i+2)
//  P4:B(0,1,2i+2) P5:A(0,1,2i+2) P6:B(1,0,2i+3) P7:A(1,0,2i+3) P8:B(1,1,2i+3)
// Reg sets: afA (odd phases) / afB (even); bfX (P1,P2,P5,P6) / bfY (P3,P4,P7,P8).

#define VM8 asm volatile("s_waitcnt vmcnt(8)" ::: "memory")

#define SA(buf, ks, kt) do {                                      \
    const u16* g_ = Ag + (((kt) & 15) * 64 + (ks) * 32);          \
    u16* l_ = ldsA + (buf) * 32768 + (ks) * 8192;                 \
    GLL(g_, l_); GLL(g_ + 16 * 1024, l_ + 512); } while (0)

#define SB(buf, ks, kt) do {                                      \
    const u16* g_ = Wg + (((kt) & 15) * 64 + (ks) * 32);          \
    u16* l_ = ldsB + (buf) * 32768 + (ks) * 8192;                 \
    GLL(g_, l_); GLL(g_ + 16 * 1024, l_ + 512); } while (0)

// RD4: af frags tb=4 of (buf,ks) -> SET
#define RD4(SET, buf, ks) do {                                    \
    const u16* pA_ = aBase + (buf) * 32768 + (ks) * 8192;         \
    _Pragma("unroll") for (int t_ = 0; t_ < 4; t_++)              \
      SET[t_] = *(const short8*)(pA_ + aOff[4 + t_]); } while (0)

// RD8: af frags tb=0 + bf frags of (buf,ks)
#define RD8(ASET, BSET, buf, ks) do {                             \
    const u16* pA_ = aBase + (buf) * 32768 + (ks) * 8192;         \
    const u16* pB_ = bBase + (buf) * 32768 + (ks) * 8192;         \
    _Pragma("unroll") for (int t_ = 0; t_ < 4; t_++)              \
      ASET[t_] = *(const short8*)(pA_ + aOff[t_]);                \
    _Pragma("unroll") for (int u_ = 0; u_ < 4; u_++)              \
      BSET[u_] = *(const short8*)(pB_ + bOff[u_]); } while (0)

#define MFMA16(AF, BF, tb)                                        \
    _Pragma("unroll") for (int t_ = 0; t_ < 4; t_++) {            \
      acc[(tb) + t_][0] = __builtin_amdgcn_mfma_f32_16x16x32_bf16(AF[t_], BF[0], acc[(tb) + t_][0], 0, 0, 0); \
      acc[(tb) + t_][1] = __builtin_amdgcn_mfma_f32_16x16x32_bf16(AF[t_], BF[1], acc[(tb) + t_][1], 0, 0, 0); \
      acc[(tb) + t_][2] = __builtin_amdgcn_mfma_f32_16x16x32_bf16(AF[t_], BF[2], acc[(tb) + t_][2], 0, 0, 0); \
      acc[(tb) + t_][3] = __builtin_amdgcn_mfma_f32_16x16x32_bf16(AF[t_], BF[3], acc[(tb) + t_][3], 0, 0, 0); \
    }

#define PH(AFC, BFC, tb, RDOP, N, STG) do {                       \
    RDOP;                                                         \
    asm volatile("s_waitcnt lgkmcnt(" #N ")" ::: "memory");       \
    __builtin_amdgcn_sched_barrier(0);                            \
    __builtin_amdgcn_s_setprio(1);                                \
    MFMA16(AFC, BFC, tb);                                         \
    __builtin_amdgcn_s_setprio(0);                                \
    STG;                                                          \
    VM8;                                                          \
    __builtin_amdgcn_s_barrier();                                 \
  } while (0)

// prologue: 7 units (kt0 full + A/B(1,0) + B(1,1) of kt1) = 14 GLL.
// vmcnt(8) => 6 GLL landed = units A00,B00,A01; barrier publishes; then
// RD(P1) reads A00,B00.
#define MAIN_8PHASE_LOOP                                          \
  short8 afA[4], afB[4], bfX[4], bfY[4];                          \
  SA(0, 0, 0); SB(0, 0, 0); SA(0, 1, 0); SB(0, 1, 0);             \
  SA(1, 0, 1); SB(1, 0, 1); SB(1, 1, 1);                          \
  VM8;                                                            \
  __builtin_amdgcn_s_barrier();                                   \
  asm volatile("" ::: "memory");                                  \
  RD8(afA, bfX, 0, 0);                                            \
  _Pragma("unroll 1")                                             \
  for (int i = 0; i < 8; i++) {                                   \
    PH(afA, bfX, 0, RD4(afB, 0, 0),        4, SA(1, 1, 2 * i + 1)); \
    PH(afB, bfX, 4, RD8(afA, bfY, 0, 1),   8, SB(0, 0, 2 * i + 2)); \
    PH(afA, bfY, 0, RD4(afB, 0, 1),        4, SA(0, 0, 2 * i + 2)); \
    PH(afB, bfY, 4, RD8(afA, bfX, 1, 0),   8, SB(0, 1, 2 * i + 2)); \
    PH(afA, bfX, 0, RD4(afB, 1, 0),        4, SA(0, 1, 2 * i + 2)); \
    PH(afB, bfX, 4, RD8(afA, bfY, 1, 1),   8, SB(1, 0, 2 * i + 3)); \
    PH(afA, bfY, 0, RD4(afB, 1, 1),        4, SA(1, 0, 2 * i + 3)); \
    PH(afB, bfY, 4, RD8(afA, bfX, 0, 0),   8, SB(1, 1, 2 * i + 3)); \
  }

__global__ __launch_bounds__(512, 2) void gemm_qkv(const u16* __restrict__ A,
                                                   const u16* __restrict__ Wqkv,
                                                   const float* __restrict__ biasQKV,
                                                   u16* __restrict__ phiq,
                                                   u16* __restrict__ phiKT,
                                                   u16* __restrict__ vT) {
  const int K = 1024;
  // 768 blocks: 8 XCD rectangles of 8 tile_m x 12 tile_n
  const int bId = blockIdx.x;
  const int xcd = bId & 7, s = bId >> 3;     // s 0..95
  const int tile_m = xcd * 8 + s / 12;       // 0..63
  const int tile_n = s % 12;                 // 0..11
  const int region = tile_n >> 2;            // 0=Q,1=K,2=V

  const int tid = threadIdx.x, lane = tid & 63, wv = tid >> 6;
  const int i16 = lane & 15, q = lane >> 4;
  const int waveM = wv >> 2, waveN = wv & 3;

  __shared__ u16 smem[65536];  // 128 KiB

  // staging: wave wv stages rows [wv*32, wv*32+32) of both A and W panels
  const int r0 = wv * 32 + (lane >> 2);
  const int kc = (lane & 3) ^ ((r0 >> 1) & 3);   // pre-swizzled global k-chunk
  const u16* Ag = A + (size_t)(tile_m * 256 + r0) * K + kc * 8;
  const u16* Wg = Wqkv + (size_t)(tile_n * 256 + r0) * K + kc * 8;
  u16* ldsA = smem + wv * 1024;
  u16* ldsB = smem + 16384 + wv * 1024;

  // fragment pointers; region 0 swaps operands (A-op = W) so that both
  // epilogue paths write lane-contiguous u16x4.
  const u16* aBase = (region == 0) ? smem + 16384 : smem;
  const u16* bBase = (region == 0) ? smem : smem + 16384;
  int aOff[8], bOff[4];
#pragma unroll
  for (int t = 0; t < 8; t++) {
    int m = waveM * 128 + t * 16 + i16;
    aOff[t] = m * 32 + ((q ^ ((m >> 1) & 3)) << 3);
  }
#pragma unroll
  for (int u = 0; u < 4; u++) {
    int n = waveN * 64 + u * 16 + i16;
    bOff[u] = n * 32 + ((q ^ ((n >> 1) & 3)) << 3);
  }

  f32x4 acc[8][4] = {};

  MAIN_8PHASE_LOOP
  // (last iter staged wrapped kt&15 data that is never read; the epilogue
  //  __syncthreads drains vmcnt+lgkmcnt before smem is reused as T)

  // ---- epilogue: 2 halves via LDS T[256][132] u16 ----
  u16* T = smem;
  const int TS = 132;
  u16* dstT = (region == 1) ? phiKT : vT;
  const int bI = tile_m >> 4;
  const int lb = (tile_m & 15) * 256;

#pragma unroll
  for (int h = 0; h < 2; h++) {
    __syncthreads();
    if (waveM == h) {
      if (region == 0) {
        // acc rows = n, cols = m. T[m 0..255][n-in-half 0..127]
#pragma unroll
        for (int t = 0; t < 8; t++) {
          f32x4 b4 = *(const f32x4*)(biasQKV + tile_n * 256 + h * 128 + t * 16 + q * 4);
#pragma unroll
          for (int u = 0; u < 4; u++) {
            int cC = waveN * 64 + u * 16 + i16;
            u16x4 o;
#pragma unroll
            for (int r = 0; r < 4; r++) o[r] = f2bf(eluP1(acc[t][u][r] + b4[r]));
            *(u16x4*)(T + cC * TS + t * 16 + q * 4) = o;
          }
        }
      } else {
        // acc rows = m(l), cols = n. T[n 0..255][l-in-half 0..127]
#pragma unroll
        for (int u = 0; u < 4; u++) {
          int cC = waveN * 64 + u * 16 + i16;
          float bs = biasQKV[tile_n * 256 + cC];
#pragma unroll
          for (int t = 0; t < 8; t++) {
            u16x4 o;
#pragma unroll
            for (int r = 0; r < 4; r++) {
              float vv = acc[t][u][r] + bs;
              if (region == 1) vv = eluP1(vv);
              o[r] = f2bf(vv);
            }
            *(u16x4*)(T + cC * TS + t * 16 + q * 4) = o;
          }
        }
      }
    }
    __syncthreads();
    {
      const int Rl = tid >> 4, c16 = (tid & 15) * 8;
#pragma unroll
      for (int p = 0; p < 8; p++) {
        int R = p * 32 + Rl;
        short8 v8 = *(const short8*)(T + R * TS + c16);
        if (region == 0) {
          *(short8*)(phiq + (size_t)(tile_m * 256 + R) * DM + tile_n * 256 + h * 128 + c16) = v8;
        } else {
          int n_loc = tile_n * 256 + R - region * 1024;
          *(short8*)(dstT + ((size_t)bI * 1024 + n_loc) * 4096 + lb + h * 128 + c16) = v8;
        }
      }
    }
  }
}

// ---------------- output GEMM: out = Vnew @ WO^T + bO (fp32) ----------------
// Same 256x256 reg-dbuf template. A-op = WO rows (n), B-op = Vnew rows (l).
__global__ __launch_bounds__(512, 2) void gemm_out(const u16* __restrict__ A,
                                                   const u16* __restrict__ W,
                                                   const float* __restrict__ bias,
                                                   float* __restrict__ outp) {
  const int K = 1024;
  // 256 blocks: 8 XCD rectangles of 8 tile_m x 4 tile_n
  const int bId = blockIdx.x;
  const int xcd = bId & 7, s = bId >> 3;     // s 0..31
  const int tile_m = xcd * 8 + (s >> 2);     // 0..63
  const int tile_n = s & 3;                  // 0..3

  const int tid = threadIdx.x, lane = tid & 63, wv = tid >> 6;
  const int i16 = lane & 15, q = lane >> 4;
  const int waveM = wv >> 2, waveN = wv & 3;

  __shared__ u16 smem[65536];  // 128 KiB; epilogue Tf[256][68] f32 = 69632B

  const int r0 = wv * 32 + (lane >> 2);
  const int kc = (lane & 3) ^ ((r0 >> 1) & 3);
  const u16* Ag = A + (size_t)(tile_m * 256 + r0) * K + kc * 8;   // Vnew rows (l)
  const u16* Wg = W + (size_t)(tile_n * 256 + r0) * K + kc * 8;   // WO rows (n)
  u16* ldsA = smem + wv * 1024;
  u16* ldsB = smem + 16384 + wv * 1024;

  // A-op = W (staged in ldsB region), B-op = Vnew (staged in ldsA region)
  const u16* aBase = smem + 16384;
  const u16* bBase = smem;
  int aOff[8], bOff[4];
#pragma unroll
  for (int t = 0; t < 8; t++) {
    int m = waveM * 128 + t * 16 + i16;      // n within 256-tile
    aOff[t] = m * 32 + ((q ^ ((m >> 1) & 3)) << 3);
  }
#pragma unroll
  for (int u = 0; u < 4; u++) {
    int n = waveN * 64 + u * 16 + i16;       // l within 256-tile
    bOff[u] = n * 32 + ((q ^ ((n >> 1) & 3)) << 3);
  }

  f32x4 acc[8][4] = {};

  MAIN_8PHASE_LOOP

  // ---- epilogue: 4 quarters (64 n-cols each) via Tf[l 256][n 68pad] f32 ----
  // acc[t][u][r] = C[n = waveM*128 + t*16 + q*4 + r][l = waveN*64 + u*16 + i16]
  float* Tf = (float*)smem;
  const int TFS = 68;
#pragma unroll
  for (int qn = 0; qn < 4; qn++) {
    __syncthreads();
    if (waveM == (qn >> 1)) {
      const int tb = (qn & 1) * 4;
#pragma unroll
      for (int tt = 0; tt < 4; tt++) {
        f32x4 b4 = *(const f32x4*)(bias + tile_n * 256 + qn * 64 + tt * 16 + q * 4);
#pragma unroll
        for (int u = 0; u < 4; u++) {
          int l = waveN * 64 + u * 16 + i16;
          f32x4 o;
#pragma unroll
          for (int r = 0; r < 4; r++) o[r] = acc[tb + tt][u][r] + b4[r];
          *(f32x4*)(Tf + l * TFS + tt * 16 + q * 4) = o;
        }
      }
    }
    __syncthreads();
    {
      const int Rl = tid >> 4, j = tid & 15;
#pragma unroll
      for (int p = 0; p < 8; p++) {
        int R = p * 32 + Rl;
        f32x4 v = *(const f32x4*)(Tf + R * TFS + j * 4);
        *(f32x4*)(outp + (size_t)(tile_m * 256 + R) * DM + tile_n * 256 + qn * 64 + j * 4) = v;
      }
    }
  }
}

// ---------------- KV partial + K_sum partial (fused) ----------------
__global__ __launch_bounds__(256) void kv_partial(const u16* __restrict__ phiKT,
                                                  const u16* __restrict__ vT,
                                                  float* __restrict__ part,
                                                  float* __restrict__ ksumP) {
  int bh = blockIdx.x >> 2, chunk = blockIdx.x & 3;
  int tid = threadIdx.x, lane = tid & 63, wv = tid >> 6;
  int i16 = lane & 15, q = lane >> 4;
  const u16* Ab = phiKT + (size_t)bh * DK * SL;
  const u16* Bb = vT + (size_t)bh * DK * SL;
  int l0 = (chunk * 4 + wv) * 256;
  f32x4 acc[4][4] = {};
  float ks[4] = {};
  for (int kk = 0; kk < 256; kk += 32) {
    int col = l0 + kk + q * 8;
    short8 af[4], bfr[4];
#pragma unroll
    for (int t = 0; t < 4; t++) af[t] = *(const short8*)(Ab + (size_t)(t * 16 + i16) * SL + col);
#pragma unroll
    for (int u = 0; u < 4; u++) bfr[u] = *(const short8*)(Bb + (size_t)(u * 16 + i16) * SL + col);
#pragma unroll
    for (int t = 0; t < 4; t++)
#pragma unroll
      for (int j = 0; j < 8; j++) ks[t] += bf2f((u16)af[t][j]);
#pragma unroll
    for (int t = 0; t < 4; t++)
#pragma unroll
      for (int u = 0; u < 4; u++)
        acc[t][u] = __builtin_amdgcn_mfma_f32_16x16x32_bf16(af[t], bfr[u], acc[t][u], 0, 0, 0);
  }
  __shared__ float red[4][64][64];  // 64KB
  __shared__ float ksl[4][4][64];
#pragma unroll
  for (int t = 0; t < 4; t++)
#pragma unroll
    for (int u = 0; u < 4; u++)
#pragma unroll
      for (int r = 0; r < 4; r++)
        red[wv][t * 16 + q * 4 + r][u * 16 + i16] = acc[t][u][r];
#pragma unroll
  for (int t = 0; t < 4; t++) ksl[wv][q][t * 16 + i16] = ks[t];
  __syncthreads();
  int d = tid >> 2, mg = (tid & 3) * 16;
#pragma unroll
  for (int c = 0; c < 4; c++) {
    int m = mg + c * 4;
    f32x4 o;
#pragma unroll
    for (int r = 0; r < 4; r++)
      o[r] = red[0][d][m + r] + red[1][d][m + r] + red[2][d][m + r] + red[3][d][m + r];
    *(f32x4*)(part + ((size_t)(chunk * 64 + bh) * 64 + d) * 64 + m) = o;
  }
  if (tid < 64) {
    float s = 0.f;
#pragma unroll
    for (int w2 = 0; w2 < 4; w2++)
#pragma unroll
      for (int q2 = 0; q2 < 4; q2++) s += ksl[w2][q2][tid];
    ksumP[chunk * 4096 + bh * 64 + tid] = s;
  }
}

// ---------------- finalize: KVt (bf16, [bh][m][d]) + Ksum ----------------
__global__ __launch_bounds__(256) void kv_finalize(const float* __restrict__ part,
                                                   const float* __restrict__ ksumP,
                                                   u16* __restrict__ KVt,
                                                   float* __restrict__ Ksum) {
  int bh = blockIdx.x, tid = threadIdx.x;
  for (int e = tid; e < 4096; e += 256) {
    int d = e >> 6, m = e & 63;
    float s = part[((size_t)(0 * 64 + bh) * 64 + d) * 64 + m]
            + part[((size_t)(1 * 64 + bh) * 64 + d) * 64 + m]
            + part[((size_t)(2 * 64 + bh) * 64 + d) * 64 + m]
            + part[((size_t)(3 * 64 + bh) * 64 + d) * 64 + m];
    KVt[(size_t)bh * 4096 + m * 64 + d] = f2bf(s);
  }
  if (tid < 64) {
    float s = ksumP[0 * 4096 + bh * 64 + tid] + ksumP[1 * 4096 + bh * 64 + tid]
            + ksumP[2 * 4096 + bh * 64 + tid] + ksumP[3 * 4096 + bh * 64 + tid];
    Ksum[bh * 64 + tid] = s;
  }
}

// ---------------- V_new = (phi_q @ KV) * Z, fused in-register Z ----------------
// Z-denominator (phi_q . Ksum) is accumulated from the SAME phiq fragments the
// MFMA loads (lane (i16,q) covers cols step*32+q*8..+7 of row l), then closed
// with shfl_xor over the q-lane groups. Removes the separate phiq pass.
__global__ __launch_bounds__(256) void vnew_kernel(const u16* __restrict__ phiq,
                                                   const u16* __restrict__ KVt,
                                                   const float* __restrict__ Ksum,
                                                   u16* __restrict__ Vnew) {
  int bh = blockIdx.x >> 5, lt = blockIdx.x & 31;
  int b = bh >> 4, h = bh & 15;
  int tid = threadIdx.x, lane = tid & 63, wv = tid >> 6;
  int i16 = lane & 15, q = lane >> 4;
  int waveM = wv & 1, waveL = wv >> 1;

  __shared__ u16 T[128 * 72];

  // Ksum values for this lane's 16 cols (2 steps x 8)
  f32x4 ks00 = *(const f32x4*)(Ksum + bh * 64 + q * 8);
  f32x4 ks01 = *(const f32x4*)(Ksum + bh * 64 + q * 8 + 4);
  f32x4 ks10 = *(const f32x4*)(Ksum + bh * 64 + 32 + q * 8);
  f32x4 ks11 = *(const f32x4*)(Ksum + bh * 64 + 32 + q * 8 + 4);

  f32x4 acc[2][4] = {};
  float zp[4] = {0.f, 0.f, 0.f, 0.f};
#pragma unroll
  for (int step = 0; step < 2; step++) {
    int d0 = step * 32 + q * 8;
    short8 af[2], bfr[4];
#pragma unroll
    for (int t = 0; t < 2; t++) {
      int m = waveM * 32 + t * 16 + i16;
      af[t] = *(const short8*)(KVt + (size_t)bh * 4096 + m * 64 + d0);
    }
#pragma unroll
    for (int u = 0; u < 4; u++) {
      int l = lt * 128 + waveL * 64 + u * 16 + i16;
      bfr[u] = *(const short8*)(phiq + (size_t)(b * SL + l) * DM + h * 64 + d0);
      f32x4 k0 = step == 0 ? ks00 : ks10;
      f32x4 k1 = step == 0 ? ks01 : ks11;
#pragma unroll
      for (int j = 0; j < 4; j++) zp[u] += bf2f((u16)bfr[u][j]) * k0[j];
#pragma unroll
      for (int j = 0; j < 4; j++) zp[u] += bf2f((u16)bfr[u][4 + j]) * k1[j];
    }
#pragma unroll
    for (int t = 0; t < 2; t++)
#pragma unroll
      for (int u = 0; u < 4; u++)
        acc[t][u] = __builtin_amdgcn_mfma_f32_16x16x32_bf16(af[t], bfr[u], acc[t][u], 0, 0, 0);
  }

  // close the row-dot across q-lane groups (lane bits 4,5) and invert
  float z[4];
#pragma unroll
  for (int u = 0; u < 4; u++) {
    float s = zp[u];
    s += __shfl_xor(s, 16);
    s += __shfl_xor(s, 32);
    z[u] = 1.0f / (s + 1e-5f);
  }

#pragma unroll
  for (int t = 0; t < 2; t++) {
#pragma unroll
    for (int u = 0; u < 4; u++) {
      int cI = waveL * 64 + u * 16 + i16;           // l
      int nI = waveM * 32 + t * 16 + q * 4;         // n local
      u16x4 o;
#pragma unroll
      for (int r = 0; r < 4; r++) o[r] = f2bf(acc[t][u][r] * z[u]);
      *(u16x4*)(T + cI * 72 + nI) = o;
    }
  }
  __syncthreads();
  {
    const int Rl = tid >> 3, j = tid & 7;
#pragma unroll
    for (int p = 0; p < 4; p++) {
      int R = p * 32 + Rl;
      short8 v8 = *(const short8*)(T + R * 72 + j * 8);
      *(short8*)(Vnew + (size_t)(b * SL + lt * 128 + R) * DM + h * 64 + j * 8) = v8;
    }
  }
}

extern "C" void kernel_launch(void* const* d_in, const int* in_sizes, int n_in,
                              void* d_out, int out_size, void* d_ws, size_t ws_size,
                              hipStream_t stream) {
  const float* Qf = (const float*)d_in[0];
  const float* WQ = (const float*)d_in[1];
  const float* bQ = (const float*)d_in[2];
  const float* WK = (const float*)d_in[3];
  const float* bK = (const float*)d_in[4];
  const float* WV = (const float*)d_in[5];
  const float* bV = (const float*)d_in[6];
  const float* WO = (const float*)d_in[7];
  const float* bO = (const float*)d_in[8];

  const size_t MB = 1024ull * 1024ull;
  char* ws = (char*)d_ws;
  u16* Qbf     = (u16*)(ws + 0);          // 32MB; reused as Vnew
  u16* Vnew    = (u16*)(ws + 0);
  u16* Wqkv    = (u16*)(ws + 32 * MB);    // 6MB
  u16* Wobf    = (u16*)(ws + 38 * MB);    // 2MB
  float* biasQKV = (float*)(ws + 40 * MB);// 12KB
  u16* phiq    = (u16*)(ws + 41 * MB);    // 32MB
  u16* phiKT   = (u16*)(ws + 73 * MB);    // 32MB [b][h][d][l]
  u16* vT      = (u16*)(ws + 105 * MB);   // 32MB [b][h][m][l]
  u16* KVt     = (u16*)(ws + 137 * MB);   // 512KB [bh][m][d]
  float* Ksum  = (float*)(ws + 138 * MB); // 16KB
  float* part  = (float*)(ws + 139 * MB); // 4MB
  float* ksumP = (float*)(ws + 143 * MB); // 64KB

  cvt_all<<<20492, 256, 0, stream>>>(Qf, WQ, WK, WV, WO, bQ, bK, bV,
                                     Qbf, Wqkv, Wobf, biasQKV);

  gemm_qkv<<<768, 512, 0, stream>>>(Qbf, Wqkv, biasQKV, phiq, phiKT, vT);

  kv_partial<<<256, 256, 0, stream>>>(phiKT, vT, part, ksumP);
  kv_finalize<<<64, 256, 0, stream>>>(part, ksumP, KVt, Ksum);

  vnew_kernel<<<2048, 256, 0, stream>>>(phiq, KVt, Ksum, Vnew);

  gemm_out<<<256, 512, 0, stream>>>(Vnew, Wobf, bO, (float*)d_out);
}

// Round 7
// 326.264 us; speedup vs baseline: 1.0244x; 1.0244x over previous
//
#include <hip/hip_runtime.h>

typedef unsigned short u16;
typedef unsigned int   u32;
typedef __attribute__((ext_vector_type(8))) short short8;
typedef __attribute__((ext_vector_type(4))) float f32x4;
typedef __attribute__((ext_vector_type(4))) u16   u16x4;

#define NB 4
#define SL 4096
#define DM 1024
#define NH 16
#define DK 64

__device__ __forceinline__ u16 f2bf(float f) {
  u32 u = __builtin_bit_cast(u32, f);
  u = (u + 0x7fffu + ((u >> 16) & 1u)) >> 16;
  return (u16)u;
}
__device__ __forceinline__ float bf2f(u16 v) {
  u32 u = ((u32)v) << 16;
  return __builtin_bit_cast(float, u);
}
__device__ __forceinline__ float eluP1(float x) {
  return x > 0.f ? x + 1.f : __expf(x);
}
// NOTE: the imm offset of global_load_lds applies to BOTH global and LDS
// addresses (LLVM intrinsic semantics) — always pass 0 and do pointer math.
#define GLL(gp, lp) __builtin_amdgcn_global_load_lds(     \
    (const __attribute__((address_space(1))) void*)(gp),  \
    (__attribute__((address_space(3))) void*)(lp), 16, 0, 0)

// ---------------- merged conversions ----------------
__global__ void cvt_all(const float* __restrict__ Qf,
                        const float* __restrict__ WQ, const float* __restrict__ WK,
                        const float* __restrict__ WV, const float* __restrict__ WO,
                        const float* __restrict__ bQ, const float* __restrict__ bK,
                        const float* __restrict__ bV,
                        u16* __restrict__ Qbf, u16* __restrict__ Wqkv,
                        u16* __restrict__ Wobf, float* __restrict__ biasQKV) {
  int b = blockIdx.x, tid = threadIdx.x;
  if (b < 16384) {
    int i = b * 256 + tid;
    f32x4 f = *(const f32x4*)(Qf + (size_t)i * 4);
    u16x4 o = { f2bf(f[0]), f2bf(f[1]), f2bf(f[2]), f2bf(f[3]) };
    *(u16x4*)(Qbf + (size_t)i * 4) = o;
  } else if (b < 20480) {
    int r = (b - 16384) >> 10;
    int i = ((b - 16384) & 1023) * 256 + tid;
    const float* src = r == 0 ? WQ : r == 1 ? WK : r == 2 ? WV : WO;
    u16* dst = (r == 3) ? Wobf : Wqkv + (size_t)r * 1048576;
    f32x4 f = *(const f32x4*)(src + (size_t)i * 4);
    u16x4 o = { f2bf(f[0]), f2bf(f[1]), f2bf(f[2]), f2bf(f[3]) };
    *(u16x4*)(dst + (size_t)i * 4) = o;
  } else {
    int i = (b - 20480) * 256 + tid;
    if (i < 3072) {
      float v = (i < 1024) ? bQ[i] : (i < 2048) ? bK[i - 1024] : bV[i - 2048];
      biasQKV[i] = v;
    }
  }
}

// ======== 256x256 4-ring low-barrier GEMM template ========
// Theory (R6 post-mortem): per-phase barriers reset all 8 waves to the
// slowest wave's DS-queue tail (~550 cyc skew) every ~620-cyc MFMA burst ->
// DS and MFMA pipes add instead of overlap. Fix: barrier every 2 K-tiles.
// LDS (u16 elems, 128 KiB): A ring buf b @ b*8192 (256 rows x 32 k),
//                           B ring buf b @ 32768 + b*8192.
// Body (kt, kt+1; bufs kt&3,(kt+1)&3): stage kt+2; TILE(kt); stage kt+3;
// TILE(kt+1); vmcnt(0); s_barrier. Plain short8 LDS reads (compiler
// auto-waitcnt schedules within the 2-tile window).
// Hazards: RAW - stages kt+2/kt+3 land by body-end vmcnt(0), published by
//   the barrier, read next body. WAR - stage(kt+2) targets buf (kt-2)&3;
//   every wave's reads(kt-2) were consumed by its MFMA(kt-2) (auto-waitcnt)
//   before it reached the previous barrier, and stage issues after that
//   barrier. In-body reads touch bufs kt,kt+1 - disjoint from staged bufs.
// Tail: kt=30 body restages tiles 0,1 (valid addresses, never read; drained
//   by the epilogue __syncthreads).

#define VM0 asm volatile("s_waitcnt vmcnt(0)" ::: "memory")

#define SA(kt) do {                                               \
    const u16* g_ = Ag + (((kt) & 31) * 32);                      \
    u16* l_ = ldsA + (((kt) & 3) * 8192);                         \
    GLL(g_, l_); GLL(g_ + 16 * 1024, l_ + 512); } while (0)

#define SB(kt) do {                                               \
    const u16* g_ = Wg + (((kt) & 31) * 32);                      \
    u16* l_ = ldsB + (((kt) & 3) * 8192);                         \
    GLL(g_, l_); GLL(g_ + 16 * 1024, l_ + 512); } while (0)

#define STG2(kt) do { SA(kt); SB(kt); } while (0)

#define MFMA16(AF, BF, tb)                                        \
    _Pragma("unroll") for (int t_ = 0; t_ < 4; t_++) {            \
      acc[(tb) + t_][0] = __builtin_amdgcn_mfma_f32_16x16x32_bf16(AF[t_], BF[0], acc[(tb) + t_][0], 0, 0, 0); \
      acc[(tb) + t_][1] = __builtin_amdgcn_mfma_f32_16x16x32_bf16(AF[t_], BF[1], acc[(tb) + t_][1], 0, 0, 0); \
      acc[(tb) + t_][2] = __builtin_amdgcn_mfma_f32_16x16x32_bf16(AF[t_], BF[2], acc[(tb) + t_][2], 0, 0, 0); \
      acc[(tb) + t_][3] = __builtin_amdgcn_mfma_f32_16x16x32_bf16(AF[t_], BF[3], acc[(tb) + t_][3], 0, 0, 0); \
    }

#define TILE(buf) do {                                            \
    short8 a0_[4], b_[4];                                         \
    _Pragma("unroll") for (int t_ = 0; t_ < 4; t_++)              \
      a0_[t_] = *(const short8*)(aBase + (buf) * 8192 + aOff[t_]);\
    _Pragma("unroll") for (int u_ = 0; u_ < 4; u_++)              \
      b_[u_] = *(const short8*)(bBase + (buf) * 8192 + bOff[u_]); \
    __builtin_amdgcn_s_setprio(1);                                \
    MFMA16(a0_, b_, 0);                                           \
    __builtin_amdgcn_s_setprio(0);                                \
    short8 a4_[4];                                                \
    _Pragma("unroll") for (int t_ = 0; t_ < 4; t_++)              \
      a4_[t_] = *(const short8*)(aBase + (buf) * 8192 + aOff[4 + t_]); \
    __builtin_amdgcn_s_setprio(1);                                \
    MFMA16(a4_, b_, 4);                                           \
    __builtin_amdgcn_s_setprio(0);                                \
  } while (0)

#define MAIN_RING_LOOP                                            \
  STG2(0); STG2(1);                                               \
  VM0;                                                            \
  __builtin_amdgcn_s_barrier();                                   \
  asm volatile("" ::: "memory");                                  \
  _Pragma("unroll 1")                                             \
  for (int kt = 0; kt < 32; kt += 2) {                            \
    STG2(kt + 2);                                                 \
    TILE(kt & 3);                                                 \
    STG2(kt + 3);                                                 \
    TILE((kt + 1) & 3);                                           \
    VM0;                                                          \
    __builtin_amdgcn_s_barrier();                                 \
  }

__global__ __launch_bounds__(512, 2) void gemm_qkv(const u16* __restrict__ A,
                                                   const u16* __restrict__ Wqkv,
                                                   const float* __restrict__ biasQKV,
                                                   u16* __restrict__ phiq,
                                                   u16* __restrict__ phiKT,
                                                   u16* __restrict__ vT) {
  const int K = 1024;
  // 768 blocks: 8 XCD rectangles of 8 tile_m x 12 tile_n
  const int bId = blockIdx.x;
  const int xcd = bId & 7, s = bId >> 3;     // s 0..95
  const int tile_m = xcd * 8 + s / 12;       // 0..63
  const int tile_n = s % 12;                 // 0..11
  const int region = tile_n >> 2;            // 0=Q,1=K,2=V

  const int tid = threadIdx.x, lane = tid & 63, wv = tid >> 6;
  const int i16 = lane & 15, q = lane >> 4;
  const int waveM = wv >> 2, waveN = wv & 3;

  __shared__ u16 smem[65536];  // 128 KiB: A ring [0,32768), B ring [32768,65536)

  // staging: wave wv stages rows [wv*32, wv*32+32) of both A and W panels
  const int r0 = wv * 32 + (lane >> 2);
  const int kc = (lane & 3) ^ ((r0 >> 1) & 3);   // pre-swizzled global k-chunk
  const u16* Ag = A + (size_t)(tile_m * 256 + r0) * K + kc * 8;
  const u16* Wg = Wqkv + (size_t)(tile_n * 256 + r0) * K + kc * 8;
  u16* ldsA = smem + wv * 1024;
  u16* ldsB = smem + 32768 + wv * 1024;

  // fragment pointers; region 0 swaps operands (A-op = W) so that both
  // epilogue paths write lane-contiguous u16x4.
  const u16* aBase = (region == 0) ? smem + 32768 : smem;
  const u16* bBase = (region == 0) ? smem : smem + 32768;
  int aOff[8], bOff[4];
#pragma unroll
  for (int t = 0; t < 8; t++) {
    int m = waveM * 128 + t * 16 + i16;
    aOff[t] = m * 32 + ((q ^ ((m >> 1) & 3)) << 3);
  }
#pragma unroll
  for (int u = 0; u < 4; u++) {
    int n = waveN * 64 + u * 16 + i16;
    bOff[u] = n * 32 + ((q ^ ((n >> 1) & 3)) << 3);
  }

  f32x4 acc[8][4] = {};

  MAIN_RING_LOOP

  // ---- epilogue: 2 halves via LDS T[256][132] u16 ----
  u16* T = smem;
  const int TS = 132;
  u16* dstT = (region == 1) ? phiKT : vT;
  const int bI = tile_m >> 4;
  const int lb = (tile_m & 15) * 256;

#pragma unroll
  for (int h = 0; h < 2; h++) {
    __syncthreads();
    if (waveM == h) {
      if (region == 0) {
        // acc rows = n, cols = m. T[m 0..255][n-in-half 0..127]
#pragma unroll
        for (int t = 0; t < 8; t++) {
          f32x4 b4 = *(const f32x4*)(biasQKV + tile_n * 256 + h * 128 + t * 16 + q * 4);
#pragma unroll
          for (int u = 0; u < 4; u++) {
            int cC = waveN * 64 + u * 16 + i16;
            u16x4 o;
#pragma unroll
            for (int r = 0; r < 4; r++) o[r] = f2bf(eluP1(acc[t][u][r] + b4[r]));
            *(u16x4*)(T + cC * TS + t * 16 + q * 4) = o;
          }
        }
      } else {
        // acc rows = m(l), cols = n. T[n 0..255][l-in-half 0..127]
#pragma unroll
        for (int u = 0; u < 4; u++) {
          int cC = waveN * 64 + u * 16 + i16;
          float bs = biasQKV[tile_n * 256 + cC];
#pragma unroll
          for (int t = 0; t < 8; t++) {
            u16x4 o;
#pragma unroll
            for (int r = 0; r < 4; r++) {
              float vv = acc[t][u][r] + bs;
              if (region == 1) vv = eluP1(vv);
              o[r] = f2bf(vv);
            }
            *(u16x4*)(T + cC * TS + t * 16 + q * 4) = o;
          }
        }
      }
    }
    __syncthreads();
    {
      const int Rl = tid >> 4, c16 = (tid & 15) * 8;
#pragma unroll
      for (int p = 0; p < 8; p++) {
        int R = p * 32 + Rl;
        short8 v8 = *(const short8*)(T + R * TS + c16);
        if (region == 0) {
          *(short8*)(phiq + (size_t)(tile_m * 256 + R) * DM + tile_n * 256 + h * 128 + c16) = v8;
        } else {
          int n_loc = tile_n * 256 + R - region * 1024;
          *(short8*)(dstT + ((size_t)bI * 1024 + n_loc) * 4096 + lb + h * 128 + c16) = v8;
        }
      }
    }
  }
}

// ---------------- output GEMM: out = Vnew @ WO^T + bO (fp32) ----------------
// Same 4-ring template. A-op = WO rows (n), B-op = Vnew rows (l).
__global__ __launch_bounds__(512, 2) void gemm_out(const u16* __restrict__ A,
                                                   const u16* __restrict__ W,
                                                   const float* __restrict__ bias,
                                                   float* __restrict__ outp) {
  const int K = 1024;
  // 256 blocks: 8 XCD rectangles of 8 tile_m x 4 tile_n
  const int bId = blockIdx.x;
  const int xcd = bId & 7, s = bId >> 3;     // s 0..31
  const int tile_m = xcd * 8 + (s >> 2);     // 0..63
  const int tile_n = s & 3;                  // 0..3

  const int tid = threadIdx.x, lane = tid & 63, wv = tid >> 6;
  const int i16 = lane & 15, q = lane >> 4;
  const int waveM = wv >> 2, waveN = wv & 3;

  __shared__ u16 smem[65536];  // 128 KiB; epilogue Tf[256][68] f32 = 69632B

  const int r0 = wv * 32 + (lane >> 2);
  const int kc = (lane & 3) ^ ((r0 >> 1) & 3);
  const u16* Ag = A + (size_t)(tile_m * 256 + r0) * K + kc * 8;   // Vnew rows (l)
  const u16* Wg = W + (size_t)(tile_n * 256 + r0) * K + kc * 8;   // WO rows (n)
  u16* ldsA = smem + wv * 1024;
  u16* ldsB = smem + 32768 + wv * 1024;

  // A-op = W (staged in B ring), B-op = Vnew (staged in A ring)
  const u16* aBase = smem + 32768;
  const u16* bBase = smem;
  int aOff[8], bOff[4];
#pragma unroll
  for (int t = 0; t < 8; t++) {
    int m = waveM * 128 + t * 16 + i16;      // n within 256-tile
    aOff[t] = m * 32 + ((q ^ ((m >> 1) & 3)) << 3);
  }
#pragma unroll
  for (int u = 0; u < 4; u++) {
    int n = waveN * 64 + u * 16 + i16;       // l within 256-tile
    bOff[u] = n * 32 + ((q ^ ((n >> 1) & 3)) << 3);
  }

  f32x4 acc[8][4] = {};

  MAIN_RING_LOOP

  // ---- epilogue: 4 quarters (64 n-cols each) via Tf[l 256][n 68pad] f32 ----
  // acc[t][u][r] = C[n = waveM*128 + t*16 + q*4 + r][l = waveN*64 + u*16 + i16]
  float* Tf = (float*)smem;
  const int TFS = 68;
#pragma unroll
  for (int qn = 0; qn < 4; qn++) {
    __syncthreads();
    if (waveM == (qn >> 1)) {
      const int tb = (qn & 1) * 4;
#pragma unroll
      for (int tt = 0; tt < 4; tt++) {
        f32x4 b4 = *(const f32x4*)(bias + tile_n * 256 + qn * 64 + tt * 16 + q * 4);
#pragma unroll
        for (int u = 0; u < 4; u++) {
          int l = waveN * 64 + u * 16 + i16;
          f32x4 o;
#pragma unroll
          for (int r = 0; r < 4; r++) o[r] = acc[tb + tt][u][r] + b4[r];
          *(f32x4*)(Tf + l * TFS + tt * 16 + q * 4) = o;
        }
      }
    }
    __syncthreads();
    {
      const int Rl = tid >> 4, j = tid & 15;
#pragma unroll
      for (int p = 0; p < 8; p++) {
        int R = p * 32 + Rl;
        f32x4 v = *(const f32x4*)(Tf + R * TFS + j * 4);
        *(f32x4*)(outp + (size_t)(tile_m * 256 + R) * DM + tile_n * 256 + qn * 64 + j * 4) = v;
      }
    }
  }
}

// ---------------- KV partial + K_sum partial (fused) ----------------
__global__ __launch_bounds__(256) void kv_partial(const u16* __restrict__ phiKT,
                                                  const u16* __restrict__ vT,
                                                  float* __restrict__ part,
                                                  float* __restrict__ ksumP) {
  int bh = blockIdx.x >> 2, chunk = blockIdx.x & 3;
  int tid = threadIdx.x, lane = tid & 63, wv = tid >> 6;
  int i16 = lane & 15, q = lane >> 4;
  const u16* Ab = phiKT + (size_t)bh * DK * SL;
  const u16* Bb = vT + (size_t)bh * DK * SL;
  int l0 = (chunk * 4 + wv) * 256;
  f32x4 acc[4][4] = {};
  float ks[4] = {};
  for (int kk = 0; kk < 256; kk += 32) {
    int col = l0 + kk + q * 8;
    short8 af[4], bfr[4];
#pragma unroll
    for (int t = 0; t < 4; t++) af[t] = *(const short8*)(Ab + (size_t)(t * 16 + i16) * SL + col);
#pragma unroll
    for (int u = 0; u < 4; u++) bfr[u] = *(const short8*)(Bb + (size_t)(u * 16 + i16) * SL + col);
#pragma unroll
    for (int t = 0; t < 4; t++)
#pragma unroll
      for (int j = 0; j < 8; j++) ks[t] += bf2f((u16)af[t][j]);
#pragma unroll
    for (int t = 0; t < 4; t++)
#pragma unroll
      for (int u = 0; u < 4; u++)
        acc[t][u] = __builtin_amdgcn_mfma_f32_16x16x32_bf16(af[t], bfr[u], acc[t][u], 0, 0, 0);
  }
  __shared__ float red[4][64][64];  // 64KB
  __shared__ float ksl[4][4][64];
#pragma unroll
  for (int t = 0; t < 4; t++)
#pragma unroll
    for (int u = 0; u < 4; u++)
#pragma unroll
      for (int r = 0; r < 4; r++)
        red[wv][t * 16 + q * 4 + r][u * 16 + i16] = acc[t][u][r];
#pragma unroll
  for (int t = 0; t < 4; t++) ksl[wv][q][t * 16 + i16] = ks[t];
  __syncthreads();
  int d = tid >> 2, mg = (tid & 3) * 16;
#pragma unroll
  for (int c = 0; c < 4; c++) {
    int m = mg + c * 4;
    f32x4 o;
#pragma unroll
    for (int r = 0; r < 4; r++)
      o[r] = red[0][d][m + r] + red[1][d][m + r] + red[2][d][m + r] + red[3][d][m + r];
    *(f32x4*)(part + ((size_t)(chunk * 64 + bh) * 64 + d) * 64 + m) = o;
  }
  if (tid < 64) {
    float s = 0.f;
#pragma unroll
    for (int w2 = 0; w2 < 4; w2++)
#pragma unroll
      for (int q2 = 0; q2 < 4; q2++) s += ksl[w2][q2][tid];
    ksumP[chunk * 4096 + bh * 64 + tid] = s;
  }
}

// ---------------- finalize: KVt (bf16, [bh][m][d]) + Ksum ----------------
__global__ __launch_bounds__(256) void kv_finalize(const float* __restrict__ part,
                                                   const float* __restrict__ ksumP,
                                                   u16* __restrict__ KVt,
                                                   float* __restrict__ Ksum) {
  int bh = blockIdx.x, tid = threadIdx.x;
  for (int e = tid; e < 4096; e += 256) {
    int d = e >> 6, m = e & 63;
    float s = part[((size_t)(0 * 64 + bh) * 64 + d) * 64 + m]
            + part[((size_t)(1 * 64 + bh) * 64 + d) * 64 + m]
            + part[((size_t)(2 * 64 + bh) * 64 + d) * 64 + m]
            + part[((size_t)(3 * 64 + bh) * 64 + d) * 64 + m];
    KVt[(size_t)bh * 4096 + m * 64 + d] = f2bf(s);
  }
  if (tid < 64) {
    float s = ksumP[0 * 4096 + bh * 64 + tid] + ksumP[1 * 4096 + bh * 64 + tid]
            + ksumP[2 * 4096 + bh * 64 + tid] + ksumP[3 * 4096 + bh * 64 + tid];
    Ksum[bh * 64 + tid] = s;
  }
}

// ---------------- V_new = (phi_q @ KV) * Z, fused in-register Z ----------------
// Z-denominator (phi_q . Ksum) is accumulated from the SAME phiq fragments the
// MFMA loads (lane (i16,q) covers cols step*32+q*8..+7 of row l), then closed
// with shfl_xor over the q-lane groups. Removes the separate phiq pass.
__global__ __launch_bounds__(256) void vnew_kernel(const u16* __restrict__ phiq,
                                                   const u16* __restrict__ KVt,
                                                   const float* __restrict__ Ksum,
                                                   u16* __restrict__ Vnew) {
  int bh = blockIdx.x >> 5, lt = blockIdx.x & 31;
  int b = bh >> 4, h = bh & 15;
  int tid = threadIdx.x, lane = tid & 63, wv = tid >> 6;
  int i16 = lane & 15, q = lane >> 4;
  int waveM = wv & 1, waveL = wv >> 1;

  __shared__ u16 T[128 * 72];

  // Ksum values for this lane's 16 cols (2 steps x 8)
  f32x4 ks00 = *(const f32x4*)(Ksum + bh * 64 + q * 8);
  f32x4 ks01 = *(const f32x4*)(Ksum + bh * 64 + q * 8 + 4);
  f32x4 ks10 = *(const f32x4*)(Ksum + bh * 64 + 32 + q * 8);
  f32x4 ks11 = *(const f32x4*)(Ksum + bh * 64 + 32 + q * 8 + 4);

  f32x4 acc[2][4] = {};
  float zp[4] = {0.f, 0.f, 0.f, 0.f};
#pragma unroll
  for (int step = 0; step < 2; step++) {
    int d0 = step * 32 + q * 8;
    short8 af[2], bfr[4];
#pragma unroll
    for (int t = 0; t < 2; t++) {
      int m = waveM * 32 + t * 16 + i16;
      af[t] = *(const short8*)(KVt + (size_t)bh * 4096 + m * 64 + d0);
    }
#pragma unroll
    for (int u = 0; u < 4; u++) {
      int l = lt * 128 + waveL * 64 + u * 16 + i16;
      bfr[u] = *(const short8*)(phiq + (size_t)(b * SL + l) * DM + h * 64 + d0);
      f32x4 k0 = step == 0 ? ks00 : ks10;
      f32x4 k1 = step == 0 ? ks01 : ks11;
#pragma unroll
      for (int j = 0; j < 4; j++) zp[u] += bf2f((u16)bfr[u][j]) * k0[j];
#pragma unroll
      for (int j = 0; j < 4; j++) zp[u] += bf2f((u16)bfr[u][4 + j]) * k1[j];
    }
#pragma unroll
    for (int t = 0; t < 2; t++)
#pragma unroll
      for (int u = 0; u < 4; u++)
        acc[t][u] = __builtin_amdgcn_mfma_f32_16x16x32_bf16(af[t], bfr[u], acc[t][u], 0, 0, 0);
  }

  // close the row-dot across q-lane groups (lane bits 4,5) and invert
  float z[4];
#pragma unroll
  for (int u = 0; u < 4; u++) {
    float s = zp[u];
    s += __shfl_xor(s, 16);
    s += __shfl_xor(s, 32);
    z[u] = 1.0f / (s + 1e-5f);
  }

#pragma unroll
  for (int t = 0; t < 2; t++) {
#pragma unroll
    for (int u = 0; u < 4; u++) {
      int cI = waveL * 64 + u * 16 + i16;           // l
      int nI = waveM * 32 + t * 16 + q * 4;         // n local
      u16x4 o;
#pragma unroll
      for (int r = 0; r < 4; r++) o[r] = f2bf(acc[t][u][r] * z[u]);
      *(u16x4*)(T + cI * 72 + nI) = o;
    }
  }
  __syncthreads();
  {
    const int Rl = tid >> 3, j = tid & 7;
#pragma unroll
    for (int p = 0; p < 4; p++) {
      int R = p * 32 + Rl;
      short8 v8 = *(const short8*)(T + R * 72 + j * 8);
      *(short8*)(Vnew + (size_t)(b * SL + lt * 128 + R) * DM + h * 64 + j * 8) = v8;
    }
  }
}

extern "C" void kernel_launch(void* const* d_in, const int* in_sizes, int n_in,
                              void* d_out, int out_size, void* d_ws, size_t ws_size,
                              hipStream_t stream) {
  const float* Qf = (const float*)d_in[0];
  const float* WQ = (const float*)d_in[1];
  const float* bQ = (const float*)d_in[2];
  const float* WK = (const float*)d_in[3];
  const float* bK = (const float*)d_in[4];
  const float* WV = (const float*)d_in[5];
  const float* bV = (const float*)d_in[6];
  const float* WO = (const float*)d_in[7];
  const float* bO = (const float*)d_in[8];

  const size_t MB = 1024ull * 1024ull;
  char* ws = (char*)d_ws;
  u16* Qbf     = (u16*)(ws + 0);          // 32MB; reused as Vnew
  u16* Vnew    = (u16*)(ws + 0);
  u16* Wqkv    = (u16*)(ws + 32 * MB);    // 6MB
  u16* Wobf    = (u16*)(ws + 38 * MB);    // 2MB
  float* biasQKV = (float*)(ws + 40 * MB);// 12KB
  u16* phiq    = (u16*)(ws + 41 * MB);    // 32MB
  u16* phiKT   = (u16*)(ws + 73 * MB);    // 32MB [b][h][d][l]
  u16* vT      = (u16*)(ws + 105 * MB);   // 32MB [b][h][m][l]
  u16* KVt     = (u16*)(ws + 137 * MB);   // 512KB [bh][m][d]
  float* Ksum  = (float*)(ws + 138 * MB); // 16KB
  float* part  = (float*)(ws + 139 * MB); // 4MB
  float* ksumP = (float*)(ws + 143 * MB); // 64KB

  cvt_all<<<20492, 256, 0, stream>>>(Qf, WQ, WK, WV, WO, bQ, bK, bV,
                                     Qbf, Wqkv, Wobf, biasQKV);

  gemm_qkv<<<768, 512, 0, stream>>>(Qbf, Wqkv, biasQKV, phiq, phiKT, vT);

  kv_partial<<<256, 256, 0, stream>>>(phiKT, vT, part, ksumP);
  kv_finalize<<<64, 256, 0, stream>>>(part, ksumP, KVt, Ksum);

  vnew_kernel<<<2048, 256, 0, stream>>>(phiq, KVt, Ksum, Vnew);

  gemm_out<<<256, 512, 0, stream>>>(Vnew, Wobf, bO, (float*)d_out);
}